// Round 8
// baseline (612.317 us; speedup 1.0000x reference)
//
#include <hip/hip_runtime.h>

#define DEV __device__ __forceinline__

typedef float f32x4 __attribute__((ext_vector_type(4)));
typedef short bf16x8 __attribute__((ext_vector_type(8)));

DEV unsigned short f2bf(float f) {
  union { float f; unsigned int u; } v; v.f = f;
  unsigned int r = v.u + 0x7FFFu + ((v.u >> 16) & 1u);
  return (unsigned short)(r >> 16);
}
DEV float bf2f(unsigned short h) {
  union { unsigned int u; float f; } v; v.u = ((unsigned int)h) << 16;
  return v.f;
}

// raw v_exp_f32 (2^x), skipping libm denormal fixup. Args here are <= ~4.
DEV float fexp2(float x) {
#if defined(__has_builtin)
#if __has_builtin(__builtin_amdgcn_exp2f)
  return __builtin_amdgcn_exp2f(x);
#else
  float r; asm("v_exp_f32 %0, %1" : "=v"(r) : "v"(x)); return r;
#endif
#else
  float r; asm("v_exp_f32 %0, %1" : "=v"(r) : "v"(x)); return r;
#endif
}

DEV void gload16(const void* g, void* l) {
  __builtin_amdgcn_global_load_lds((const __attribute__((address_space(1))) void*)g,
                                   (__attribute__((address_space(3))) void*)l, 16, 0, 0);
}

// ---------------------------------------------------------------------------
// GEMM: C[i,j] = sum_k A[i,k] * B[j,k]  (A: M x Kstride bf16, B: N x Kstride)
// BM x BN tile, BK=64, 4 waves (2x2), 16x16x32 bf16 MFMA, global_load_lds.
// 2-phase double-buffered K-loop: stage(kt+1) issued before compute(kt),
// single vmcnt(0)+barrier per K-step (prefetch latency hides under MFMA).
// K = iterated depth (<= Kstride); koff = blockIdx.z * K (split-K support).
// EPI 0: O1[i*N+j] = v
// EPI 1: Ob[i*N+j] = bf16(gelu(v + bias[j]))
// EPI 2: O1[i*N+j] = v + bias[j] + resid[i*N+j]
// EPI 3: Ob[i*N+j] = bf16(softplus(v + bias[j]))
// EPI 5: j<2048: Ob[i*2048+j]=bf16(v)  else Ob2[i*2048+(j-2048)]=bf16(silu(v))
// EPI 6: O1[(z*M+i)*N+j] = v   (split-K partial)
// ---------------------------------------------------------------------------
template <int BM, int BN, int EPI>
__global__ __launch_bounds__(256) void gemm_bt(
    const unsigned short* __restrict__ A, const unsigned short* __restrict__ B,
    float* __restrict__ O1, unsigned short* __restrict__ Ob, unsigned short* __restrict__ Ob2,
    const float* __restrict__ bias, const float* __restrict__ resid,
    int M, int N, int K, int Kstride)
{
  constexpr int MR = BM / 32, NR = BN / 32;
  __shared__ unsigned short As[2 * BM * 64];
  __shared__ unsigned short Bs[2 * BN * 64];
  const int tid = threadIdx.x;
  const int wave = tid >> 6;
  const int lane = tid & 63;
  const int brow = blockIdx.x * BM;
  const int bcol = blockIdx.y * BN;
  const int koff = blockIdx.z * K;
  const int wr = (wave >> 1) * (BM / 2), wc = (wave & 1) * (BN / 2);
  const int lr = lane & 15, lq = lane >> 4;

  f32x4 acc[MR][NR];
#pragma unroll
  for (int m = 0; m < MR; ++m)
#pragma unroll
    for (int n = 0; n < NR; ++n)
#pragma unroll
      for (int j = 0; j < 4; ++j) acc[m][n][j] = 0.f;

  const size_t strideA = (size_t)Kstride * 2;  // bytes per row
  const char* Abase = (const char*)A + (size_t)brow * strideA + (size_t)koff * 2;
  const char* Bbase = (const char*)B + (size_t)bcol * strideA + (size_t)koff * 2;
  const int srow = tid >> 3;            // 0..31 within a 32-row chunk
  const int scol = (tid & 7) * 16;      // byte col 0..112

  auto stage = [&](int buf, int k0) {
#pragma unroll
    for (int is = 0; is < MR; ++is) {
      char* la = (char*)As + buf * (BM * 128) + is * 4096 + wave * 1024;  // wave-uniform
      gload16(Abase + (size_t)(is * 32 + srow) * strideA + (size_t)k0 * 2 + scol, la);
    }
#pragma unroll
    for (int is = 0; is < NR; ++is) {
      char* lb = (char*)Bs + buf * (BN * 128) + is * 4096 + wave * 1024;
      gload16(Bbase + (size_t)(is * 32 + srow) * strideA + (size_t)k0 * 2 + scol, lb);
    }
  };
  auto compute = [&](int buf) {
    const unsigned short* Ab = As + buf * (BM * 64);
    const unsigned short* Bb = Bs + buf * (BN * 64);
#pragma unroll
    for (int kk = 0; kk < 2; ++kk) {
      bf16x8 av[MR], bv[NR];
      const int ko = kk * 32 + lq * 8;
#pragma unroll
      for (int m = 0; m < MR; ++m)
        av[m] = *(const bf16x8*)&Ab[(wr + m * 16 + lr) * 64 + ko];
#pragma unroll
      for (int n = 0; n < NR; ++n)
        bv[n] = *(const bf16x8*)&Bb[(wc + n * 16 + lr) * 64 + ko];
#pragma unroll
      for (int m = 0; m < MR; ++m)
#pragma unroll
        for (int n = 0; n < NR; ++n)
          acc[m][n] = __builtin_amdgcn_mfma_f32_16x16x32_bf16(av[m], bv[n], acc[m][n], 0, 0, 0);
    }
  };

  const int nk = K >> 6;
  stage(0, 0);
  asm volatile("s_waitcnt vmcnt(0)" ::: "memory");
  __syncthreads();
  int cur = 0;
  for (int kt = 0; kt < nk - 1; ++kt) {
    stage(cur ^ 1, (kt + 1) << 6);   // prefetch next tile (latency hides under compute)
    compute(cur);
    asm volatile("s_waitcnt vmcnt(0)" ::: "memory");
    __syncthreads();
    cur ^= 1;
  }
  compute(cur);

#pragma unroll
  for (int m = 0; m < MR; ++m) {
#pragma unroll
    for (int n = 0; n < NR; ++n) {
      const int col = bcol + wc + n * 16 + lr;
      const int row0 = brow + wr + m * 16 + lq * 4;
#pragma unroll
      for (int j = 0; j < 4; ++j) {
        const int row = row0 + j;
        float v = acc[m][n][j];
        if (EPI == 0) {
          O1[(size_t)row * N + col] = v;
        } else if (EPI == 1) {
          v += bias[col];
          v = 0.5f * v * (1.f + erff(v * 0.70710678118654752f));
          Ob[(size_t)row * N + col] = f2bf(v);
        } else if (EPI == 2) {
          v += bias[col] + resid[(size_t)row * N + col];
          O1[(size_t)row * N + col] = v;
        } else if (EPI == 3) {
          v += bias[col];
          v = (v > 20.f) ? v : log1pf(expf(v));
          Ob[(size_t)row * N + col] = f2bf(v);
        } else if (EPI == 5) {
          if (col < 2048) Ob[(size_t)row * 2048 + col] = f2bf(v);
          else Ob2[(size_t)row * 2048 + (col - 2048)] = f2bf(v / (1.f + expf(-v)));
        } else {  // 6: split-K partial
          O1[((size_t)blockIdx.z * M + row) * N + col] = v;
        }
      }
    }
  }
}

// Reduce split-K partials for x_proj; fuses adt16 (dt-rank cols, bf16) extract.
__global__ __launch_bounds__(256) void xproj_reduce(
    const float* __restrict__ pbuf, float* __restrict__ dbc,
    unsigned short* __restrict__ adt)
{
  const int idx = blockIdx.x * 256 + threadIdx.x;  // 4096*128
  float s = 0.f;
#pragma unroll
  for (int z = 0; z < 8; ++z) s += pbuf[(size_t)z * 524288 + idx];
  dbc[idx] = s;
  const int r = idx & 127;
  if (r < 64) adt[(size_t)(idx >> 7) * 64 + r] = f2bf(s);
}

// ---------------------------------------------------------------------------
// LayerNorm over last dim (1024), writes bf16. One block per row.
// ---------------------------------------------------------------------------
__global__ __launch_bounds__(256) void ln_kernel(
    const float* __restrict__ x, const float* __restrict__ w,
    const float* __restrict__ b, unsigned short* __restrict__ out)
{
  const int row = blockIdx.x;
  const int tid = threadIdx.x;
  const float4 v = ((const float4*)(x + (size_t)row * 1024))[tid];
  float s = v.x + v.y + v.z + v.w;
  float sq = v.x * v.x + v.y * v.y + v.z * v.z + v.w * v.w;
#pragma unroll
  for (int m = 32; m >= 1; m >>= 1) { s += __shfl_xor(s, m); sq += __shfl_xor(sq, m); }
  __shared__ float ss[4], sqs[4];
  const int wave = tid >> 6;
  if ((tid & 63) == 0) { ss[wave] = s; sqs[wave] = sq; }
  __syncthreads();
  s = ss[0] + ss[1] + ss[2] + ss[3];
  sq = sqs[0] + sqs[1] + sqs[2] + sqs[3];
  const float mean = s * (1.f / 1024.f);
  const float var = sq * (1.f / 1024.f) - mean * mean;
  const float rstd = rsqrtf(var + 1e-5f);
  const float4 wv = ((const float4*)w)[tid];
  const float4 bv = ((const float4*)b)[tid];
  ushort4 o;
  o.x = f2bf((v.x - mean) * rstd * wv.x + bv.x);
  o.y = f2bf((v.y - mean) * rstd * wv.y + bv.y);
  o.z = f2bf((v.z - mean) * rstd * wv.z + bv.z);
  o.w = f2bf((v.w - mean) * rstd * wv.w + bv.w);
  ((ushort4*)(out + (size_t)row * 1024))[tid] = o;
}

// ---------------------------------------------------------------------------
// Depthwise causal conv (K=4) + bias + SiLU. xc16 token-major bf16 (4096x2048).
// ---------------------------------------------------------------------------
__global__ __launch_bounds__(256) void conv_silu_kernel(
    const unsigned short* __restrict__ xc16, const float* __restrict__ cw,
    const float* __restrict__ cb, unsigned short* __restrict__ u16)
{
  const int idx = blockIdx.x * 256 + threadIdx.x;
  const int d = idx & 2047;
  const int i = idx >> 11;
  const int t = i & 2047;
  float acc = cb[d];
#pragma unroll
  for (int k = 0; k < 4; ++k) {
    const int tt = t - 3 + k;
    if (tt >= 0) acc += bf2f(xc16[(size_t)(i - 3 + k) * 2048 + d]) * cw[d * 4 + k];
  }
  const float s = acc / (1.f + expf(-acc));
  u16[idx] = f2bf(s);
}

// ---------------------------------------------------------------------------
// Fused weight conversion: all 6 weight tensors in one launch.
// ---------------------------------------------------------------------------
__global__ __launch_bounds__(256) void cvt_weights(
    const float* __restrict__ w_in, unsigned short* __restrict__ d_in16,
    const float* __restrict__ w_ff1, unsigned short* __restrict__ d_ff1,
    const float* __restrict__ w_ff2, unsigned short* __restrict__ d_ff2,
    const float* __restrict__ w_out, unsigned short* __restrict__ d_out16,
    const float* __restrict__ w_dt, unsigned short* __restrict__ d_dt,
    const float* __restrict__ w_xp, unsigned short* __restrict__ d_xp)
{
  const int bid = blockIdx.x;
  const int tid = threadIdx.x;
  if (bid < 14336) {
    const float* s; unsigned short* d; int lb;
    if (bid < 4096)       { s = w_in;  d = d_in16;  lb = bid; }
    else if (bid < 8192)  { s = w_ff1; d = d_ff1;   lb = bid - 4096; }
    else if (bid < 12288) { s = w_ff2; d = d_ff2;   lb = bid - 8192; }
    else                  { s = w_out; d = d_out16; lb = bid - 12288; }
    const int i = lb * 256 + tid;
    const float4 v = ((const float4*)s)[i];
    ((ushort4*)d)[i] = make_ushort4(f2bf(v.x), f2bf(v.y), f2bf(v.z), f2bf(v.w));
  } else if (bid < 14464) {
    const int i = (bid - 14336) * 256 + tid;
    const float4 v = ((const float4*)w_dt)[i];
    ((ushort4*)d_dt)[i] = make_ushort4(f2bf(v.x), f2bf(v.y), f2bf(v.z), f2bf(v.w));
  } else {
    const int i = (bid - 14464) * 256 + tid;
    const int r = (i * 4) >> 11;
    ushort4 o;
    if (r < 96) {
      const float4 v = ((const float4*)w_xp)[i];
      o = make_ushort4(f2bf(v.x), f2bf(v.y), f2bf(v.z), f2bf(v.w));
    } else {
      o = make_ushort4(0, 0, 0, 0);
    }
    ((ushort4*)d_xp)[i] = o;
  }
}

// ---------------------------------------------------------------------------
// State-in-register chunk-parallel selective scan. One lane owns one channel's
// 16 states in registers. dlt/u/z bf16 token-major (coalesced); B,C broadcast
// per step via wave-uniform SGPR-base pointers.
// ---------------------------------------------------------------------------
template <int NC>
__global__ __launch_bounds__(256) void scan_p1(
    const unsigned short* __restrict__ dlt, const unsigned short* __restrict__ u16,
    const float* __restrict__ dbc, const float* __restrict__ A_log,
    float* __restrict__ hpart, float* __restrict__ sdtp)
{
  constexpr int L = 2048 / NC;
  const int tid = threadIdx.x;
  const int c = blockIdx.x % NC;
  const int chg = blockIdx.x / NC;
  const int id = chg * 256 + tid;
  const int dch = id & 2047;
  const int b = id >> 11;
  float al2[16], h[16];
#pragma unroll
  for (int s = 0; s < 16; ++s) {
    al2[s] = -fexp2(A_log[dch * 16 + s] * 1.44269504f) * 1.44269504f;
    h[s] = 0.f;
  }
  const int i0 = b * 2048 + c * L;
  const int i0u = __builtin_amdgcn_readfirstlane(i0);
  const unsigned short* dptr = dlt + (size_t)i0 * 2048 + dch;
  const unsigned short* uptr = u16 + (size_t)i0 * 2048 + dch;
  const float* Bptr = dbc + (size_t)i0u * 128 + 64;  // wave-uniform
  float sdt = 0.f;
  for (int t = 0; t < L; ++t) {
    const float dt = bf2f(*dptr);
    const float uu = bf2f(*uptr);
    const float dtu = dt * uu;
    const f32x4 B0 = *(const f32x4*)(Bptr + 0);
    const f32x4 B1 = *(const f32x4*)(Bptr + 4);
    const f32x4 B2 = *(const f32x4*)(Bptr + 8);
    const f32x4 B3 = *(const f32x4*)(Bptr + 12);
    sdt += dt;
#pragma unroll
    for (int s = 0; s < 16; ++s) {
      const float Bv = (s < 4) ? B0[s & 3] : (s < 8) ? B1[s & 3] : (s < 12) ? B2[s & 3] : B3[s & 3];
      h[s] = fexp2(dt * al2[s]) * h[s] + dtu * Bv;
    }
    dptr += 2048; uptr += 2048; Bptr += 128;
  }
  float* hp = hpart + ((size_t)(b * NC + c) * 2048 + dch) * 16;
#pragma unroll
  for (int s = 0; s < 16; ++s) hp[s] = h[s];
  sdtp[(size_t)(b * NC + c) * 2048 + dch] = sdt;
}

// Exclusive prefix over chunk summaries: one thread per (b, channel, state).
__global__ __launch_bounds__(256) void scan_prefix(
    const float* __restrict__ hpart, const float* __restrict__ sdtp,
    const float* __restrict__ A_log, float* __restrict__ hpre, int NC)
{
  const int g = blockIdx.x * 256 + threadIdx.x;  // 65536
  const int s = g & 15;
  const int dch = (g >> 4) & 2047;
  const int b = g >> 15;
  const float al2 = -fexp2(A_log[dch * 16 + s] * 1.44269504f) * 1.44269504f;
  float run = 0.f;
  for (int c = 0; c < NC; ++c) {
    const size_t base = ((size_t)(b * NC + c) * 2048 + dch) * 16 + s;
    hpre[base] = run;
    run = fexp2(al2 * sdtp[(size_t)(b * NC + c) * 2048 + dch]) * run + hpart[base];
  }
}

template <int NC>
__global__ __launch_bounds__(256) void scan_p2(
    const unsigned short* __restrict__ dlt, const unsigned short* __restrict__ u16,
    const float* __restrict__ dbc, const unsigned short* __restrict__ zs16,
    const float* __restrict__ A_log, const float* __restrict__ Dskip,
    const float* __restrict__ hpre, unsigned short* __restrict__ gated)
{
  constexpr int L = 2048 / NC;
  const int tid = threadIdx.x;
  const int c = blockIdx.x % NC;
  const int chg = blockIdx.x / NC;
  const int id = chg * 256 + tid;
  const int dch = id & 2047;
  const int b = id >> 11;
  float al2[16], h[16];
#pragma unroll
  for (int s = 0; s < 16; ++s)
    al2[s] = -fexp2(A_log[dch * 16 + s] * 1.44269504f) * 1.44269504f;
  const float* hb = hpre + ((size_t)(b * NC + c) * 2048 + dch) * 16;
#pragma unroll
  for (int s = 0; s < 16; ++s) h[s] = hb[s];
  const float Dsk = Dskip[dch];
  const int i0 = b * 2048 + c * L;
  const int i0u = __builtin_amdgcn_readfirstlane(i0);
  const unsigned short* dptr = dlt + (size_t)i0 * 2048 + dch;
  const unsigned short* uptr = u16 + (size_t)i0 * 2048 + dch;
  const unsigned short* zptr = zs16 + (size_t)i0 * 2048 + dch;
  const float* Bptr = dbc + (size_t)i0u * 128 + 64;  // wave-uniform
  unsigned short* gptr = gated + (size_t)i0 * 2048 + dch;
  for (int t = 0; t < L; ++t) {
    const float dt = bf2f(*dptr);
    const float uu = bf2f(*uptr);
    const float zz = bf2f(*zptr);
    const float dtu = dt * uu;
    const f32x4 B0 = *(const f32x4*)(Bptr + 0);
    const f32x4 B1 = *(const f32x4*)(Bptr + 4);
    const f32x4 B2 = *(const f32x4*)(Bptr + 8);
    const f32x4 B3 = *(const f32x4*)(Bptr + 12);
    const f32x4 C0 = *(const f32x4*)(Bptr + 16);
    const f32x4 C1 = *(const f32x4*)(Bptr + 20);
    const f32x4 C2 = *(const f32x4*)(Bptr + 24);
    const f32x4 C3 = *(const f32x4*)(Bptr + 28);
    float y0 = 0.f, y1 = 0.f, y2 = 0.f, y3 = 0.f;
#pragma unroll
    for (int s = 0; s < 16; ++s) {
      const float Bv = (s < 4) ? B0[s & 3] : (s < 8) ? B1[s & 3] : (s < 12) ? B2[s & 3] : B3[s & 3];
      const float Cv = (s < 4) ? C0[s & 3] : (s < 8) ? C1[s & 3] : (s < 12) ? C2[s & 3] : C3[s & 3];
      h[s] = fexp2(dt * al2[s]) * h[s] + dtu * Bv;
      if ((s & 3) == 0) y0 += h[s] * Cv;
      else if ((s & 3) == 1) y1 += h[s] * Cv;
      else if ((s & 3) == 2) y2 += h[s] * Cv;
      else y3 += h[s] * Cv;
    }
    const float y = (y0 + y1) + (y2 + y3);
    *gptr = f2bf((y + uu * Dsk) * zz);
    dptr += 2048; uptr += 2048; zptr += 2048; Bptr += 128; gptr += 2048;
  }
}

// ---------------------------------------------------------------------------
extern "C" void kernel_launch(void* const* d_in, const int* in_sizes, int n_in,
                              void* d_out, int out_size, void* d_ws, size_t ws_size,
                              hipStream_t stream) {
  const float* x         = (const float*)d_in[0];
  const float* ln1_w     = (const float*)d_in[1];
  const float* ln1_b     = (const float*)d_in[2];
  const float* in_proj_w = (const float*)d_in[3];
  const float* conv_w    = (const float*)d_in[4];
  const float* conv_b    = (const float*)d_in[5];
  const float* x_proj_w  = (const float*)d_in[6];
  const float* dt_w      = (const float*)d_in[7];
  const float* dt_b      = (const float*)d_in[8];
  const float* A_log     = (const float*)d_in[9];
  const float* Dskip     = (const float*)d_in[10];
  const float* out_proj_w= (const float*)d_in[11];
  const float* ln2_w     = (const float*)d_in[12];
  const float* ln2_b     = (const float*)d_in[13];
  const float* ff1_w     = (const float*)d_in[14];
  const float* ff1_b     = (const float*)d_in[15];
  const float* ff2_w     = (const float*)d_in[16];
  const float* ff2_b     = (const float*)d_in[17];
  float* out = (float*)d_out;

  char* ws = (char*)d_ws;
  size_t off = 0;
  auto alloc = [&](size_t bytes) {
    char* p = ws + off;
    off += (bytes + 255) & ~(size_t)255;
    return p;
  };
  unsigned short* w16_in  = (unsigned short*)alloc(4096ull * 1024 * 2);
  unsigned short* w16_xp  = (unsigned short*)alloc(128ull * 2048 * 2);
  unsigned short* w16_dt  = (unsigned short*)alloc(2048ull * 64 * 2);
  unsigned short* w16_out = (unsigned short*)alloc(1024ull * 2048 * 2);
  unsigned short* w16_ff1 = (unsigned short*)alloc(4096ull * 1024 * 2);
  unsigned short* w16_ff2 = (unsigned short*)alloc(1024ull * 4096 * 2);
  unsigned short* y16     = (unsigned short*)alloc(4096ull * 1024 * 2);  // later: sdtp
  char* slotX             = alloc(4096ull * 2048 * 4);   // xc16 -> hpre -> c2+t2_16
  unsigned short* u16     = (unsigned short*)alloc(4096ull * 2048 * 2);
  char* slotA             = alloc(2048ull * 4096 * 4);   // hpart -> gated16 -> h16
  unsigned short* zs16    = (unsigned short*)alloc(4096ull * 2048 * 2);
  float* dbc              = (float*)alloc(4096ull * 128 * 4);
  unsigned short* adt16   = (unsigned short*)alloc(4096ull * 64 * 2);
  char* slotD             = alloc(2048ull * 4096 * 4);   // pbuf -> dlt16
  (void)ws_size; (void)in_sizes; (void)n_in; (void)out_size;

  constexpr int NC = 128;
  unsigned short* xc16 = (unsigned short*)slotX;        // in_proj out, dead after conv
  float* hpre  = (float*)slotX;                         // prefix out, dead after p2 (33.5MB exact)
  float* c2 = (float*)slotX;                            // out_proj out (16.7MB)
  unsigned short* t2_16 = (unsigned short*)(slotX + 4096ull * 1024 * 4);
  float* hpart = (float*)slotA;                         // p1 out, dead after prefix
  unsigned short* gated16 = (unsigned short*)slotA;     // p2 out over dead hpart
  unsigned short* h16 = (unsigned short*)slotA;         // ff1 out over dead gated
  float* pbuf  = (float*)slotD;                         // x_proj split-K partials (16.8MB)
  unsigned short* dlt16 = (unsigned short*)slotD;       // dt out over dead pbuf
  float* sdtp  = (float*)y16;                           // y16 dead after in_proj

  // fused weight conversions to bf16 (single launch)
  cvt_weights<<<14720, 256, 0, stream>>>(in_proj_w, w16_in, ff1_w, w16_ff1,
                                         ff2_w, w16_ff2, out_proj_w, w16_out,
                                         dt_w, w16_dt, x_proj_w, w16_xp);

  // pipeline
  ln_kernel<<<4096, 256, 0, stream>>>(x, ln1_w, ln1_b, y16);
  gemm_bt<128, 128, 5><<<dim3(32, 32), 256, 0, stream>>>(y16, w16_in, nullptr, xc16, zs16, nullptr, nullptr, 4096, 4096, 1024, 1024);
  conv_silu_kernel<<<32768, 256, 0, stream>>>(xc16, conv_w, conv_b, u16);
  gemm_bt<128, 128, 6><<<dim3(32, 1, 8), 256, 0, stream>>>(u16, w16_xp, pbuf, nullptr, nullptr, nullptr, nullptr, 4096, 128, 256, 2048);
  xproj_reduce<<<2048, 256, 0, stream>>>(pbuf, dbc, adt16);
  gemm_bt<128, 128, 3><<<dim3(32, 16), 256, 0, stream>>>(adt16, w16_dt, nullptr, dlt16, nullptr, dt_b, nullptr, 4096, 2048, 64, 64);
  scan_p1<NC><<<16 * NC, 256, 0, stream>>>(dlt16, u16, dbc, A_log, hpart, sdtp);
  scan_prefix<<<256, 256, 0, stream>>>(hpart, sdtp, A_log, hpre, NC);
  scan_p2<NC><<<16 * NC, 256, 0, stream>>>(dlt16, u16, dbc, zs16, A_log, Dskip, hpre, gated16);
  gemm_bt<128, 64, 0><<<dim3(32, 16), 256, 0, stream>>>(gated16, w16_out, c2, nullptr, nullptr, nullptr, nullptr, 4096, 1024, 2048, 2048);
  ln_kernel<<<4096, 256, 0, stream>>>(c2, ln2_w, ln2_b, t2_16);
  gemm_bt<128, 128, 1><<<dim3(32, 32), 256, 0, stream>>>(t2_16, w16_ff1, nullptr, h16, nullptr, ff1_b, nullptr, 4096, 4096, 1024, 1024);
  gemm_bt<128, 64, 2><<<dim3(32, 16), 256, 0, stream>>>(h16, w16_ff2, out, nullptr, nullptr, ff2_b, x, 4096, 1024, 4096, 4096);
}

// Round 9
// 580.470 us; speedup vs baseline: 1.0549x; 1.0549x over previous
//
#include <hip/hip_runtime.h>

#define DEV __device__ __forceinline__

typedef float f32x4 __attribute__((ext_vector_type(4)));
typedef short bf16x8 __attribute__((ext_vector_type(8)));

DEV unsigned short f2bf(float f) {
  union { float f; unsigned int u; } v; v.f = f;
  unsigned int r = v.u + 0x7FFFu + ((v.u >> 16) & 1u);
  return (unsigned short)(r >> 16);
}
DEV float bf2f(unsigned short h) {
  union { unsigned int u; float f; } v; v.u = ((unsigned int)h) << 16;
  return v.f;
}

// raw v_exp_f32 (2^x), skipping libm denormal fixup. Args here are <= ~4.
DEV float fexp2(float x) {
#if defined(__has_builtin)
#if __has_builtin(__builtin_amdgcn_exp2f)
  return __builtin_amdgcn_exp2f(x);
#else
  float r; asm("v_exp_f32 %0, %1" : "=v"(r) : "v"(x)); return r;
#endif
#else
  float r; asm("v_exp_f32 %0, %1" : "=v"(r) : "v"(x)); return r;
#endif
}

DEV void gload16(const void* g, void* l) {
  __builtin_amdgcn_global_load_lds((const __attribute__((address_space(1))) void*)g,
                                   (__attribute__((address_space(3))) void*)l, 16, 0, 0);
}

// ---------------------------------------------------------------------------
// GEMM: C[i,j] = sum_k A[i,k] * B[j,k]  (A: M x Kstride bf16, B: N x Kstride)
// BM x BN tile, BK=64, 4 waves (2x2), 16x16x32 bf16 MFMA, global_load_lds.
// 1-phase K-loop (measured faster than 2-phase dbuf at this size, r8).
// K = iterated depth (<= Kstride); koff = blockIdx.z * K (split-K support).
// EPI 0: O1[i*N+j] = v
// EPI 1: Ob[i*N+j] = bf16(gelu(v + bias[j]))
// EPI 3: Ob[i*N+j] = bf16(softplus(v + bias[j]))
// EPI 5: j<2048: Ob[i*2048+j]=bf16(v)  else Ob2[i*2048+(j-2048)]=bf16(silu(v))
// EPI 6: O1[(z*M+i)*N+j] = v   (split-K partial)
// ---------------------------------------------------------------------------
template <int BM, int BN, int EPI>
__global__ __launch_bounds__(256) void gemm_bt(
    const unsigned short* __restrict__ A, const unsigned short* __restrict__ B,
    float* __restrict__ O1, unsigned short* __restrict__ Ob, unsigned short* __restrict__ Ob2,
    const float* __restrict__ bias, const float* __restrict__ resid,
    int M, int N, int K, int Kstride)
{
  constexpr int MR = BM / 32, NR = BN / 32;
  __shared__ unsigned short As[BM * 64];
  __shared__ unsigned short Bs[BN * 64];
  const int tid = threadIdx.x;
  const int wave = tid >> 6;
  const int lane = tid & 63;
  const int brow = blockIdx.x * BM;
  const int bcol = blockIdx.y * BN;
  const int koff = blockIdx.z * K;
  const int wr = (wave >> 1) * (BM / 2), wc = (wave & 1) * (BN / 2);
  const int lr = lane & 15, lq = lane >> 4;

  f32x4 acc[MR][NR];
#pragma unroll
  for (int m = 0; m < MR; ++m)
#pragma unroll
    for (int n = 0; n < NR; ++n)
#pragma unroll
      for (int j = 0; j < 4; ++j) acc[m][n][j] = 0.f;

  const size_t strideA = (size_t)Kstride * 2;  // bytes per row
  const char* Abase = (const char*)A + (size_t)brow * strideA + (size_t)koff * 2;
  const char* Bbase = (const char*)B + (size_t)bcol * strideA + (size_t)koff * 2;
  const int srow = tid >> 3;            // 0..31 within a 32-row chunk
  const int scol = (tid & 7) * 16;      // byte col 0..112

  for (int k0 = 0; k0 < K; k0 += 64) {
#pragma unroll
    for (int is = 0; is < MR; ++is) {
      char* la = (char*)As + is * 4096 + wave * 1024;  // wave-uniform LDS base
      gload16(Abase + (size_t)(is * 32 + srow) * strideA + (size_t)k0 * 2 + scol, la);
    }
#pragma unroll
    for (int is = 0; is < NR; ++is) {
      char* lb = (char*)Bs + is * 4096 + wave * 1024;
      gload16(Bbase + (size_t)(is * 32 + srow) * strideA + (size_t)k0 * 2 + scol, lb);
    }
    asm volatile("s_waitcnt vmcnt(0)" ::: "memory");
    __syncthreads();
#pragma unroll
    for (int kk = 0; kk < 2; ++kk) {
      bf16x8 av[MR], bv[NR];
      const int ko = kk * 32 + lq * 8;
#pragma unroll
      for (int m = 0; m < MR; ++m)
        av[m] = *(const bf16x8*)&As[(wr + m * 16 + lr) * 64 + ko];
#pragma unroll
      for (int n = 0; n < NR; ++n)
        bv[n] = *(const bf16x8*)&Bs[(wc + n * 16 + lr) * 64 + ko];
#pragma unroll
      for (int m = 0; m < MR; ++m)
#pragma unroll
        for (int n = 0; n < NR; ++n)
          acc[m][n] = __builtin_amdgcn_mfma_f32_16x16x32_bf16(av[m], bv[n], acc[m][n], 0, 0, 0);
    }
    __syncthreads();
  }

#pragma unroll
  for (int m = 0; m < MR; ++m) {
#pragma unroll
    for (int n = 0; n < NR; ++n) {
      const int col = bcol + wc + n * 16 + lr;
      const int row0 = brow + wr + m * 16 + lq * 4;
#pragma unroll
      for (int j = 0; j < 4; ++j) {
        const int row = row0 + j;
        float v = acc[m][n][j];
        if (EPI == 0) {
          O1[(size_t)row * N + col] = v;
        } else if (EPI == 1) {
          v += bias[col];
          v = 0.5f * v * (1.f + erff(v * 0.70710678118654752f));
          Ob[(size_t)row * N + col] = f2bf(v);
        } else if (EPI == 3) {
          v += bias[col];
          v = (v > 20.f) ? v : log1pf(expf(v));
          Ob[(size_t)row * N + col] = f2bf(v);
        } else if (EPI == 5) {
          if (col < 2048) Ob[(size_t)row * 2048 + col] = f2bf(v);
          else Ob2[(size_t)row * 2048 + (col - 2048)] = f2bf(v / (1.f + expf(-v)));
        } else {  // 6: split-K partial
          O1[((size_t)blockIdx.z * M + row) * N + col] = v;
        }
      }
    }
  }
}

// Sum split-K×2 partials (N=1024). FUSE 0: plain -> O1. FUSE 1: + bias[col]
// + resid -> O1 (ff2 final output, fp32).
template <int FUSE>
__global__ __launch_bounds__(256) void reduce2_kernel(
    const float* __restrict__ pbuf, float* __restrict__ O1,
    const float* __restrict__ bias, const float* __restrict__ resid)
{
  const int idx = blockIdx.x * 256 + threadIdx.x;   // over M*N/4 float4s
  const float4 a = ((const float4*)pbuf)[idx];
  const float4 b = ((const float4*)(pbuf + 4194304))[idx];
  float4 o;
  o.x = a.x + b.x; o.y = a.y + b.y; o.z = a.z + b.z; o.w = a.w + b.w;
  if (FUSE == 1) {
    const int col = (idx & 255) * 4;
    const float4 bi = *(const float4*)(bias + col);
    const float4 rv = ((const float4*)resid)[idx];
    o.x += bi.x + rv.x; o.y += bi.y + rv.y; o.z += bi.z + rv.z; o.w += bi.w + rv.w;
  }
  ((float4*)O1)[idx] = o;
}

// Reduce split-K x16 partials for x_proj; fuses adt16 (dt-rank cols) extract.
__global__ __launch_bounds__(256) void xproj_reduce(
    const float* __restrict__ pbuf, float* __restrict__ dbc,
    unsigned short* __restrict__ adt)
{
  const int idx = blockIdx.x * 256 + threadIdx.x;  // 4096*128
  float s = 0.f;
#pragma unroll
  for (int z = 0; z < 16; ++z) s += pbuf[(size_t)z * 524288 + idx];
  dbc[idx] = s;
  const int r = idx & 127;
  if (r < 64) adt[(size_t)(idx >> 7) * 64 + r] = f2bf(s);
}

// ---------------------------------------------------------------------------
// LayerNorm over last dim (1024), writes bf16. One block per row.
// ---------------------------------------------------------------------------
__global__ __launch_bounds__(256) void ln_kernel(
    const float* __restrict__ x, const float* __restrict__ w,
    const float* __restrict__ b, unsigned short* __restrict__ out)
{
  const int row = blockIdx.x;
  const int tid = threadIdx.x;
  const float4 v = ((const float4*)(x + (size_t)row * 1024))[tid];
  float s = v.x + v.y + v.z + v.w;
  float sq = v.x * v.x + v.y * v.y + v.z * v.z + v.w * v.w;
#pragma unroll
  for (int m = 32; m >= 1; m >>= 1) { s += __shfl_xor(s, m); sq += __shfl_xor(sq, m); }
  __shared__ float ss[4], sqs[4];
  const int wave = tid >> 6;
  if ((tid & 63) == 0) { ss[wave] = s; sqs[wave] = sq; }
  __syncthreads();
  s = ss[0] + ss[1] + ss[2] + ss[3];
  sq = sqs[0] + sqs[1] + sqs[2] + sqs[3];
  const float mean = s * (1.f / 1024.f);
  const float var = sq * (1.f / 1024.f) - mean * mean;
  const float rstd = rsqrtf(var + 1e-5f);
  const float4 wv = ((const float4*)w)[tid];
  const float4 bv = ((const float4*)b)[tid];
  ushort4 o;
  o.x = f2bf((v.x - mean) * rstd * wv.x + bv.x);
  o.y = f2bf((v.y - mean) * rstd * wv.y + bv.y);
  o.z = f2bf((v.z - mean) * rstd * wv.z + bv.z);
  o.w = f2bf((v.w - mean) * rstd * wv.w + bv.w);
  ((ushort4*)(out + (size_t)row * 1024))[tid] = o;
}

// ---------------------------------------------------------------------------
// Depthwise causal conv (K=4) + bias + SiLU. xc16 token-major bf16 (4096x2048).
// ---------------------------------------------------------------------------
__global__ __launch_bounds__(256) void conv_silu_kernel(
    const unsigned short* __restrict__ xc16, const float* __restrict__ cw,
    const float* __restrict__ cb, unsigned short* __restrict__ u16)
{
  const int idx = blockIdx.x * 256 + threadIdx.x;
  const int d = idx & 2047;
  const int i = idx >> 11;
  const int t = i & 2047;
  float acc = cb[d];
#pragma unroll
  for (int k = 0; k < 4; ++k) {
    const int tt = t - 3 + k;
    if (tt >= 0) acc += bf2f(xc16[(size_t)(i - 3 + k) * 2048 + d]) * cw[d * 4 + k];
  }
  const float s = acc / (1.f + expf(-acc));
  u16[idx] = f2bf(s);
}

// ---------------------------------------------------------------------------
// Fused weight conversion: all 6 weight tensors in one launch.
// ---------------------------------------------------------------------------
__global__ __launch_bounds__(256) void cvt_weights(
    const float* __restrict__ w_in, unsigned short* __restrict__ d_in16,
    const float* __restrict__ w_ff1, unsigned short* __restrict__ d_ff1,
    const float* __restrict__ w_ff2, unsigned short* __restrict__ d_ff2,
    const float* __restrict__ w_out, unsigned short* __restrict__ d_out16,
    const float* __restrict__ w_dt, unsigned short* __restrict__ d_dt,
    const float* __restrict__ w_xp, unsigned short* __restrict__ d_xp)
{
  const int bid = blockIdx.x;
  const int tid = threadIdx.x;
  if (bid < 14336) {
    const float* s; unsigned short* d; int lb;
    if (bid < 4096)       { s = w_in;  d = d_in16;  lb = bid; }
    else if (bid < 8192)  { s = w_ff1; d = d_ff1;   lb = bid - 4096; }
    else if (bid < 12288) { s = w_ff2; d = d_ff2;   lb = bid - 8192; }
    else                  { s = w_out; d = d_out16; lb = bid - 12288; }
    const int i = lb * 256 + tid;
    const float4 v = ((const float4*)s)[i];
    ((ushort4*)d)[i] = make_ushort4(f2bf(v.x), f2bf(v.y), f2bf(v.z), f2bf(v.w));
  } else if (bid < 14464) {
    const int i = (bid - 14336) * 256 + tid;
    const float4 v = ((const float4*)w_dt)[i];
    ((ushort4*)d_dt)[i] = make_ushort4(f2bf(v.x), f2bf(v.y), f2bf(v.z), f2bf(v.w));
  } else {
    const int i = (bid - 14464) * 256 + tid;
    const int r = (i * 4) >> 11;
    ushort4 o;
    if (r < 96) {
      const float4 v = ((const float4*)w_xp)[i];
      o = make_ushort4(f2bf(v.x), f2bf(v.y), f2bf(v.z), f2bf(v.w));
    } else {
      o = make_ushort4(0, 0, 0, 0);
    }
    ((ushort4*)d_xp)[i] = o;
  }
}

// ---------------------------------------------------------------------------
// State-in-register chunk-parallel selective scan. One lane owns one channel's
// 16 states in registers. dlt/u/z bf16 token-major (coalesced); B,C broadcast
// per step via wave-uniform SGPR-base pointers.
// ---------------------------------------------------------------------------
template <int NC>
__global__ __launch_bounds__(256) void scan_p1(
    const unsigned short* __restrict__ dlt, const unsigned short* __restrict__ u16,
    const float* __restrict__ dbc, const float* __restrict__ A_log,
    float* __restrict__ hpart, float* __restrict__ sdtp)
{
  constexpr int L = 2048 / NC;
  const int tid = threadIdx.x;
  const int c = blockIdx.x % NC;
  const int chg = blockIdx.x / NC;
  const int id = chg * 256 + tid;
  const int dch = id & 2047;
  const int b = id >> 11;
  float al2[16], h[16];
#pragma unroll
  for (int s = 0; s < 16; ++s) {
    al2[s] = -fexp2(A_log[dch * 16 + s] * 1.44269504f) * 1.44269504f;
    h[s] = 0.f;
  }
  const int i0 = b * 2048 + c * L;
  const int i0u = __builtin_amdgcn_readfirstlane(i0);
  const unsigned short* dptr = dlt + (size_t)i0 * 2048 + dch;
  const unsigned short* uptr = u16 + (size_t)i0 * 2048 + dch;
  const float* Bptr = dbc + (size_t)i0u * 128 + 64;  // wave-uniform
  float sdt = 0.f;
  for (int t = 0; t < L; ++t) {
    const float dt = bf2f(*dptr);
    const float uu = bf2f(*uptr);
    const float dtu = dt * uu;
    const f32x4 B0 = *(const f32x4*)(Bptr + 0);
    const f32x4 B1 = *(const f32x4*)(Bptr + 4);
    const f32x4 B2 = *(const f32x4*)(Bptr + 8);
    const f32x4 B3 = *(const f32x4*)(Bptr + 12);
    sdt += dt;
#pragma unroll
    for (int s = 0; s < 16; ++s) {
      const float Bv = (s < 4) ? B0[s & 3] : (s < 8) ? B1[s & 3] : (s < 12) ? B2[s & 3] : B3[s & 3];
      h[s] = fexp2(dt * al2[s]) * h[s] + dtu * Bv;
    }
    dptr += 2048; uptr += 2048; Bptr += 128;
  }
  float* hp = hpart + ((size_t)(b * NC + c) * 2048 + dch) * 16;
#pragma unroll
  for (int s = 0; s < 16; ++s) hp[s] = h[s];
  sdtp[(size_t)(b * NC + c) * 2048 + dch] = sdt;
}

// Exclusive prefix over chunk summaries: one thread per (b, channel, state).
__global__ __launch_bounds__(256) void scan_prefix(
    const float* __restrict__ hpart, const float* __restrict__ sdtp,
    const float* __restrict__ A_log, float* __restrict__ hpre, int NC)
{
  const int g = blockIdx.x * 256 + threadIdx.x;  // 65536
  const int s = g & 15;
  const int dch = (g >> 4) & 2047;
  const int b = g >> 15;
  const float al2 = -fexp2(A_log[dch * 16 + s] * 1.44269504f) * 1.44269504f;
  float run = 0.f;
  for (int c = 0; c < NC; ++c) {
    const size_t base = ((size_t)(b * NC + c) * 2048 + dch) * 16 + s;
    hpre[base] = run;
    run = fexp2(al2 * sdtp[(size_t)(b * NC + c) * 2048 + dch]) * run + hpart[base];
  }
}

template <int NC>
__global__ __launch_bounds__(256) void scan_p2(
    const unsigned short* __restrict__ dlt, const unsigned short* __restrict__ u16,
    const float* __restrict__ dbc, const unsigned short* __restrict__ zs16,
    const float* __restrict__ A_log, const float* __restrict__ Dskip,
    const float* __restrict__ hpre, unsigned short* __restrict__ gated)
{
  constexpr int L = 2048 / NC;
  const int tid = threadIdx.x;
  const int c = blockIdx.x % NC;
  const int chg = blockIdx.x / NC;
  const int id = chg * 256 + tid;
  const int dch = id & 2047;
  const int b = id >> 11;
  float al2[16], h[16];
#pragma unroll
  for (int s = 0; s < 16; ++s)
    al2[s] = -fexp2(A_log[dch * 16 + s] * 1.44269504f) * 1.44269504f;
  const float* hb = hpre + ((size_t)(b * NC + c) * 2048 + dch) * 16;
#pragma unroll
  for (int s = 0; s < 16; ++s) h[s] = hb[s];
  const float Dsk = Dskip[dch];
  const int i0 = b * 2048 + c * L;
  const int i0u = __builtin_amdgcn_readfirstlane(i0);
  const unsigned short* dptr = dlt + (size_t)i0 * 2048 + dch;
  const unsigned short* uptr = u16 + (size_t)i0 * 2048 + dch;
  const unsigned short* zptr = zs16 + (size_t)i0 * 2048 + dch;
  const float* Bptr = dbc + (size_t)i0u * 128 + 64;  // wave-uniform
  unsigned short* gptr = gated + (size_t)i0 * 2048 + dch;
  for (int t = 0; t < L; ++t) {
    const float dt = bf2f(*dptr);
    const float uu = bf2f(*uptr);
    const float zz = bf2f(*zptr);
    const float dtu = dt * uu;
    const f32x4 B0 = *(const f32x4*)(Bptr + 0);
    const f32x4 B1 = *(const f32x4*)(Bptr + 4);
    const f32x4 B2 = *(const f32x4*)(Bptr + 8);
    const f32x4 B3 = *(const f32x4*)(Bptr + 12);
    const f32x4 C0 = *(const f32x4*)(Bptr + 16);
    const f32x4 C1 = *(const f32x4*)(Bptr + 20);
    const f32x4 C2 = *(const f32x4*)(Bptr + 24);
    const f32x4 C3 = *(const f32x4*)(Bptr + 28);
    float y0 = 0.f, y1 = 0.f, y2 = 0.f, y3 = 0.f;
#pragma unroll
    for (int s = 0; s < 16; ++s) {
      const float Bv = (s < 4) ? B0[s & 3] : (s < 8) ? B1[s & 3] : (s < 12) ? B2[s & 3] : B3[s & 3];
      const float Cv = (s < 4) ? C0[s & 3] : (s < 8) ? C1[s & 3] : (s < 12) ? C2[s & 3] : C3[s & 3];
      h[s] = fexp2(dt * al2[s]) * h[s] + dtu * Bv;
      if ((s & 3) == 0) y0 += h[s] * Cv;
      else if ((s & 3) == 1) y1 += h[s] * Cv;
      else if ((s & 3) == 2) y2 += h[s] * Cv;
      else y3 += h[s] * Cv;
    }
    const float y = (y0 + y1) + (y2 + y3);
    *gptr = f2bf((y + uu * Dsk) * zz);
    dptr += 2048; uptr += 2048; zptr += 2048; Bptr += 128; gptr += 2048;
  }
}

// ---------------------------------------------------------------------------
extern "C" void kernel_launch(void* const* d_in, const int* in_sizes, int n_in,
                              void* d_out, int out_size, void* d_ws, size_t ws_size,
                              hipStream_t stream) {
  const float* x         = (const float*)d_in[0];
  const float* ln1_w     = (const float*)d_in[1];
  const float* ln1_b     = (const float*)d_in[2];
  const float* in_proj_w = (const float*)d_in[3];
  const float* conv_w    = (const float*)d_in[4];
  const float* conv_b    = (const float*)d_in[5];
  const float* x_proj_w  = (const float*)d_in[6];
  const float* dt_w      = (const float*)d_in[7];
  const float* dt_b      = (const float*)d_in[8];
  const float* A_log     = (const float*)d_in[9];
  const float* Dskip     = (const float*)d_in[10];
  const float* out_proj_w= (const float*)d_in[11];
  const float* ln2_w     = (const float*)d_in[12];
  const float* ln2_b     = (const float*)d_in[13];
  const float* ff1_w     = (const float*)d_in[14];
  const float* ff1_b     = (const float*)d_in[15];
  const float* ff2_w     = (const float*)d_in[16];
  const float* ff2_b     = (const float*)d_in[17];
  float* out = (float*)d_out;

  char* ws = (char*)d_ws;
  size_t off = 0;
  auto alloc = [&](size_t bytes) {
    char* p = ws + off;
    off += (bytes + 255) & ~(size_t)255;
    return p;
  };
  unsigned short* w16_in  = (unsigned short*)alloc(4096ull * 1024 * 2);
  unsigned short* w16_xp  = (unsigned short*)alloc(128ull * 2048 * 2);
  unsigned short* w16_dt  = (unsigned short*)alloc(2048ull * 64 * 2);
  unsigned short* w16_out = (unsigned short*)alloc(1024ull * 2048 * 2);
  unsigned short* w16_ff1 = (unsigned short*)alloc(4096ull * 1024 * 2);
  unsigned short* w16_ff2 = (unsigned short*)alloc(1024ull * 4096 * 2);
  unsigned short* y16     = (unsigned short*)alloc(4096ull * 1024 * 2);  // later: sdtp
  char* slotX             = alloc(4096ull * 2048 * 4);   // xc16 -> hpre -> c2+t2_16
  unsigned short* u16     = (unsigned short*)alloc(4096ull * 2048 * 2);
  char* slotA             = alloc(2048ull * 4096 * 4);   // hpart -> gated16 -> h16
  unsigned short* zs16    = (unsigned short*)alloc(4096ull * 2048 * 2);
  float* dbc              = (float*)alloc(4096ull * 128 * 4);
  unsigned short* adt16   = (unsigned short*)alloc(4096ull * 64 * 2);
  char* slotD             = alloc(2048ull * 4096 * 4);   // pbufX -> dlt16 -> pbuf2
  (void)ws_size; (void)in_sizes; (void)n_in; (void)out_size;

  constexpr int NC = 128;
  unsigned short* xc16 = (unsigned short*)slotX;        // in_proj out, dead after conv
  float* hpre  = (float*)slotX;                         // prefix out, dead after p2 (33.5MB exact)
  float* c2 = (float*)slotX;                            // out_proj out (16.7MB)
  unsigned short* t2_16 = (unsigned short*)(slotX + 4096ull * 1024 * 4);
  float* hpart = (float*)slotA;                         // p1 out, dead after prefix
  unsigned short* gated16 = (unsigned short*)slotA;     // p2 out over dead hpart
  unsigned short* h16 = (unsigned short*)slotA;         // ff1 out over dead gated
  float* pbufX = (float*)slotD;                         // x_proj split-K x16 partials (33.5MB)
  unsigned short* dlt16 = (unsigned short*)slotD;       // dt out over dead pbufX
  float* pbuf2 = (float*)slotD;                         // out_proj/ff2 split-K x2 partials
  float* sdtp  = (float*)y16;                           // y16 dead after in_proj

  // fused weight conversions to bf16 (single launch)
  cvt_weights<<<14720, 256, 0, stream>>>(in_proj_w, w16_in, ff1_w, w16_ff1,
                                         ff2_w, w16_ff2, out_proj_w, w16_out,
                                         dt_w, w16_dt, x_proj_w, w16_xp);

  // pipeline
  ln_kernel<<<4096, 256, 0, stream>>>(x, ln1_w, ln1_b, y16);
  gemm_bt<128, 128, 5><<<dim3(32, 32), 256, 0, stream>>>(y16, w16_in, nullptr, xc16, zs16, nullptr, nullptr, 4096, 4096, 1024, 1024);
  conv_silu_kernel<<<32768, 256, 0, stream>>>(xc16, conv_w, conv_b, u16);
  gemm_bt<128, 128, 6><<<dim3(32, 1, 16), 256, 0, stream>>>(u16, w16_xp, pbufX, nullptr, nullptr, nullptr, nullptr, 4096, 128, 128, 2048);
  xproj_reduce<<<2048, 256, 0, stream>>>(pbufX, dbc, adt16);
  gemm_bt<128, 64, 3><<<dim3(32, 32), 256, 0, stream>>>(adt16, w16_dt, nullptr, dlt16, nullptr, dt_b, nullptr, 4096, 2048, 64, 64);
  scan_p1<NC><<<16 * NC, 256, 0, stream>>>(dlt16, u16, dbc, A_log, hpart, sdtp);
  scan_prefix<<<256, 256, 0, stream>>>(hpart, sdtp, A_log, hpre, NC);
  scan_p2<NC><<<16 * NC, 256, 0, stream>>>(dlt16, u16, dbc, zs16, A_log, Dskip, hpre, gated16);
  gemm_bt<128, 64, 6><<<dim3(32, 16, 2), 256, 0, stream>>>(gated16, w16_out, pbuf2, nullptr, nullptr, nullptr, nullptr, 4096, 1024, 1024, 2048);
  reduce2_kernel<0><<<4096, 256, 0, stream>>>(pbuf2, c2, nullptr, nullptr);
  ln_kernel<<<4096, 256, 0, stream>>>(c2, ln2_w, ln2_b, t2_16);
  gemm_bt<128, 128, 1><<<dim3(32, 32), 256, 0, stream>>>(t2_16, w16_ff1, nullptr, h16, nullptr, ff1_b, nullptr, 4096, 4096, 1024, 1024);
  gemm_bt<128, 64, 6><<<dim3(32, 16, 2), 256, 0, stream>>>(h16, w16_ff2, pbuf2, nullptr, nullptr, nullptr, nullptr, 4096, 1024, 2048, 4096);
  reduce2_kernel<1><<<4096, 256, 0, stream>>>(pbuf2, out, ff2_b, x);
}